// Round 1
// baseline (74.021 us; speedup 1.0000x reference)
//
#include <hip/hip_runtime.h>
#include <math.h>

constexpr int N_ = 8, C_ = 256, H_ = 128, W_ = 128, G_ = 32;
constexpr int HW  = H_ * W_;        // 16384
constexpr int CHW = C_ * HW;        // 4194304

// Kernel 1: e[n,h,w] = (alpha/C) * mask(n,h,w) * sum_c x[n,c,h,w]
// Channel dim split 4-ways across lane groups within a wave; shfl-reduce.
__global__ __launch_bounds__(256) void sum_mask_kernel(
    const float* __restrict__ x, const float* __restrict__ bb,
    const int* __restrict__ stride_p, const int* __restrict__ epoch_p,
    float* __restrict__ e)
{
    int gtid  = blockIdx.x * 256 + threadIdx.x;
    int wave  = gtid >> 6;
    int lane  = gtid & 63;
    int s4    = wave * 16 + (lane & 15);   // spatial float4 index in [0, N*H*W/4)
    int chunk = lane >> 4;                 // which quarter of the channels
    int base  = s4 * 4;                    // spatial element index
    int n     = base / HW;
    int hw    = base - n * HW;

    const float* xp = x + (size_t)n * CHW + (size_t)(chunk * 64) * HW + hw;
    float4 s = make_float4(0.f, 0.f, 0.f, 0.f);
    #pragma unroll 8
    for (int c = 0; c < 64; ++c) {
        float4 v = *reinterpret_cast<const float4*>(xp + (size_t)c * HW);
        s.x += v.x; s.y += v.y; s.z += v.z; s.w += v.w;
    }
    // combine the 4 channel chunks (chunk id lives in lane bits 4..5)
    s.x += __shfl_xor(s.x, 16); s.y += __shfl_xor(s.y, 16);
    s.z += __shfl_xor(s.z, 16); s.w += __shfl_xor(s.w, 16);
    s.x += __shfl_xor(s.x, 32); s.y += __shfl_xor(s.y, 32);
    s.z += __shfl_xor(s.z, 32); s.w += __shfl_xor(s.w, 32);
    if (chunk != 0) return;

    float inv   = 1.0f / (float)(*stride_p);
    float alpha = 0.5f * (1.0f + cosf((float)M_PI * (float)(*epoch_p) / 22.0f));
    float scale = alpha * (1.0f / (float)C_);

    int h = hw / W_;
    int w = hw - h * W_;                   // multiple of 4
    float hf = (float)h;
    int m = 0;
    for (int g = 0; g < G_; ++g) {
        float4 bv = *reinterpret_cast<const float4*>(bb + ((size_t)n * G_ + g) * 4);
        float x1 = floorf(bv.x * inv), y1 = floorf(bv.y * inv);
        float x2 = ceilf (bv.z * inv), y2 = ceilf (bv.w * inv);
        if (hf >= y1 && hf < y2) {
            #pragma unroll
            for (int j = 0; j < 4; ++j) {
                float wf = (float)(w + j);
                if (wf >= x1 && wf < x2) m |= 1 << j;
            }
        }
    }
    float4 ev;
    ev.x = (m & 1) ? s.x * scale : 0.f;
    ev.y = (m & 2) ? s.y * scale : 0.f;
    ev.z = (m & 4) ? s.z * scale : 0.f;
    ev.w = (m & 8) ? s.w * scale : 0.f;
    *reinterpret_cast<float4*>(e + base) = ev;
}

// Kernel 2: out[n,c,h,w] = x[n,c,h,w] + e[n,h,w]
__global__ __launch_bounds__(256) void add_kernel(
    const float* __restrict__ x, const float* __restrict__ e,
    float* __restrict__ out)
{
    size_t i4   = (size_t)blockIdx.x * 256 + threadIdx.x;
    size_t base = i4 * 4;
    int n  = (int)(base / CHW);
    int hw = (int)(base % HW);
    float4 xv = *reinterpret_cast<const float4*>(x + base);
    float4 ev = *reinterpret_cast<const float4*>(e + (size_t)n * HW + hw);
    float4 o  = make_float4(xv.x + ev.x, xv.y + ev.y, xv.z + ev.z, xv.w + ev.w);
    *reinterpret_cast<float4*>(out + base) = o;
}

extern "C" void kernel_launch(void* const* d_in, const int* in_sizes, int n_in,
                              void* d_out, int out_size, void* d_ws, size_t ws_size,
                              hipStream_t stream) {
    const float* x  = (const float*)d_in[0];
    const float* bb = (const float*)d_in[1];
    const int* stride_p = (const int*)d_in[2];
    const int* epoch_p  = (const int*)d_in[3];
    float* out = (float*)d_out;
    float* e   = (float*)d_ws;   // N*H*W floats = 512 KiB

    // Kernel 1: N*H*W threads (channel-split x4, spatial float4)
    int threads1 = N_ * HW;                  // 131072
    sum_mask_kernel<<<threads1 / 256, 256, 0, stream>>>(x, bb, stride_p, epoch_p, e);

    // Kernel 2: one thread per float4 of the output
    size_t total4 = (size_t)N_ * CHW / 4;    // 8388608
    add_kernel<<<(int)(total4 / 256), 256, 0, stream>>>(x, e, out);
}

// Round 2
// 52.041 us; speedup vs baseline: 1.4224x; 1.4224x over previous
//
#include <hip/hip_runtime.h>
#include <math.h>

constexpr int N_ = 8, C_ = 256, H_ = 128, W_ = 128, G_ = 32;
constexpr int HW  = H_ * W_;        // 16384
constexpr int CHW = C_ * HW;        // 4194304
constexpr int T4   = 16;            // float4 per tile
constexpr int TPIX = 64;            // pixels per tile (half a row)

// One fused kernel: tile = 64 contiguous pixels (half a row) x all 256 channels.
// Pass 1: global -> LDS + per-quad channel partial sums (8 channels/thread).
// Reduce:  5-step LDS tree over the 32 channel-groups.
// Mask:    64 threads compute per-pixel box-union mask and e = scale*sum*mask.
// Pass 2: LDS -> out with e added. x is read from HBM exactly once.
__global__ __launch_bounds__(512) void fused_exc_kernel(
    const float* __restrict__ x, const float* __restrict__ bb,
    const int* __restrict__ stride_p, const int* __restrict__ epoch_p,
    float* __restrict__ out)
{
    __shared__ float4 xs[C_][T4];     // 64 KiB staged tile
    __shared__ float4 psum[32][T4];   // 8 KiB partial sums
    __shared__ float4 bbx[G_];        // boxes for this n
    __shared__ float  e_lds[TPIX];    // per-pixel excitation

    int bid  = blockIdx.x;
    int n    = bid >> 8;              // 8 n
    int rem  = bid & 255;
    int row  = rem >> 1;              // 128 rows
    int half = rem & 1;               // 2 half-rows

    int tid = threadIdx.x;
    int c0  = tid >> 4;               // channel group 0..31
    int q   = tid & 15;               // float4 index within tile 0..15

    if (tid < G_) bbx[tid] = reinterpret_cast<const float4*>(bb)[n * G_ + tid];

    size_t goff = (size_t)n * CHW + (size_t)c0 * HW + (size_t)row * W_ + half * TPIX + q * 4;
    const float* xp = x + goff;

    float4 s = make_float4(0.f, 0.f, 0.f, 0.f);
    #pragma unroll
    for (int k = 0; k < 8; ++k) {
        float4 v = *reinterpret_cast<const float4*>(xp + (size_t)(32 * k) * HW);
        xs[c0 + 32 * k][q] = v;
        s.x += v.x; s.y += v.y; s.z += v.z; s.w += v.w;
    }
    psum[c0][q] = s;
    __syncthreads();

    // tree-reduce the 32 channel groups down to psum[0][*]
    #pragma unroll
    for (int off = 16; off >= 1; off >>= 1) {
        if (tid < off * 16) {
            float4 a = psum[c0][q];
            float4 b = psum[c0 + off][q];
            psum[c0][q] = make_float4(a.x + b.x, a.y + b.y, a.z + b.z, a.w + b.w);
        }
        __syncthreads();
    }

    if (tid < TPIX) {
        float inv   = 1.0f / (float)(*stride_p);
        float alpha = 0.5f * (1.0f + cosf((float)M_PI * (float)(*epoch_p) / 22.0f));
        float scale = alpha / (float)C_;
        float hf = (float)row;
        float wf = (float)(half * TPIX + tid);
        bool m = false;
        for (int g = 0; g < G_; ++g) {
            float4 bv = bbx[g];
            float x1 = floorf(bv.x * inv), y1 = floorf(bv.y * inv);
            float x2 = ceilf (bv.z * inv), y2 = ceilf (bv.w * inv);
            m = m || (hf >= y1 && hf < y2 && wf >= x1 && wf < x2);
        }
        float sum = reinterpret_cast<float*>(&psum[0][0])[tid];
        e_lds[tid] = m ? sum * scale : 0.0f;
    }
    __syncthreads();

    float4 e4 = reinterpret_cast<float4*>(e_lds)[q];
    float* op = out + goff;
    #pragma unroll
    for (int k = 0; k < 8; ++k) {
        float4 v = xs[c0 + 32 * k][q];
        *reinterpret_cast<float4*>(op + (size_t)(32 * k) * HW) =
            make_float4(v.x + e4.x, v.y + e4.y, v.z + e4.z, v.w + e4.w);
    }
}

extern "C" void kernel_launch(void* const* d_in, const int* in_sizes, int n_in,
                              void* d_out, int out_size, void* d_ws, size_t ws_size,
                              hipStream_t stream) {
    const float* x  = (const float*)d_in[0];
    const float* bb = (const float*)d_in[1];
    const int* stride_p = (const int*)d_in[2];
    const int* epoch_p  = (const int*)d_in[3];
    float* out = (float*)d_out;

    int grid = N_ * H_ * 2;   // 2048 blocks, one per 64-pixel tile
    fused_exc_kernel<<<grid, 512, 0, stream>>>(x, bb, stride_p, epoch_p, out);
}

// Round 3
// 48.581 us; speedup vs baseline: 1.5237x; 1.0712x over previous
//
#include <hip/hip_runtime.h>
#include <math.h>

constexpr int N_ = 8, C_ = 256, H_ = 128, W_ = 128, G_ = 32;
constexpr int HW  = H_ * W_;        // 16384
constexpr int CHW = C_ * HW;        // 4194304
constexpr int TPIX = 64;            // pixels per tile (half a row)

// Fully register-resident fused kernel. Tile = 64 pixels x 256 channels.
// Each of 512 threads: 8 channels x 4 pixels in registers (8 float4).
// Channel reduce: shfl_xor within wave (4 groups) -> 8 wave partials in LDS
// -> ONE __syncthreads -> broadcast-read partials, per-thread mask, add, store.
__global__ __launch_bounds__(512) void fused_exc_kernel(
    const float* __restrict__ x, const float* __restrict__ bb,
    const int* __restrict__ stride_p, const int* __restrict__ epoch_p,
    float* __restrict__ out)
{
    __shared__ float4 psum[8][16];    // 2 KiB wave partials
    __shared__ float4 bbx[G_];        // boxes for this n

    int bid  = blockIdx.x;
    int n    = bid >> 8;              // 8 n
    int rem  = bid & 255;
    int row  = rem >> 1;              // 128 rows
    int half = rem & 1;               // 2 half-rows

    int tid  = threadIdx.x;
    int wv   = tid >> 6;              // wave 0..7
    int lane = tid & 63;
    int c0   = tid >> 4;              // channel group 0..31
    int q    = tid & 15;              // float4 index within the 64-pixel tile

    if (tid < G_) bbx[tid] = reinterpret_cast<const float4*>(bb)[n * G_ + tid];

    size_t goff = (size_t)n * CHW + (size_t)c0 * HW + (size_t)row * W_ + half * TPIX + q * 4;
    const float* xp = x + goff;

    float4 v[8];
    float4 s = make_float4(0.f, 0.f, 0.f, 0.f);
    #pragma unroll
    for (int k = 0; k < 8; ++k) {
        v[k] = *reinterpret_cast<const float4*>(xp + (size_t)(32 * k) * HW);
        s.x += v[k].x; s.y += v[k].y; s.z += v[k].z; s.w += v[k].w;
    }
    // fold the 4 channel-groups within this wave (chunk id = lane bits 4..5)
    s.x += __shfl_xor(s.x, 16); s.y += __shfl_xor(s.y, 16);
    s.z += __shfl_xor(s.z, 16); s.w += __shfl_xor(s.w, 16);
    s.x += __shfl_xor(s.x, 32); s.y += __shfl_xor(s.y, 32);
    s.z += __shfl_xor(s.z, 32); s.w += __shfl_xor(s.w, 32);
    if (lane < 16) psum[wv][q] = s;   // 32-channel partial for this wave
    __syncthreads();

    // combine 8 wave partials (broadcast reads: same q -> same address)
    float4 sum = psum[0][q];
    #pragma unroll
    for (int w = 1; w < 8; ++w) {
        float4 p = psum[w][q];
        sum.x += p.x; sum.y += p.y; sum.z += p.z; sum.w += p.w;
    }

    float inv   = 1.0f / (float)(*stride_p);
    float alpha = 0.5f * (1.0f + cosf((float)M_PI * (float)(*epoch_p) / 22.0f));
    float scale = alpha / (float)C_;

    // per-pixel mask for this thread's 4 pixels (redundant across c0 -- VALU idle)
    float hf = (float)row;
    float w0 = (float)(half * TPIX + q * 4);
    int m = 0;
    for (int g = 0; g < G_; ++g) {
        float4 bv = bbx[g];
        float x1 = floorf(bv.x * inv), y1 = floorf(bv.y * inv);
        float x2 = ceilf (bv.z * inv), y2 = ceilf (bv.w * inv);
        if (hf >= y1 && hf < y2) {
            #pragma unroll
            for (int j = 0; j < 4; ++j) {
                float wf = w0 + (float)j;
                if (wf >= x1 && wf < x2) m |= 1 << j;
            }
        }
    }
    float4 e4;
    e4.x = (m & 1) ? sum.x * scale : 0.f;
    e4.y = (m & 2) ? sum.y * scale : 0.f;
    e4.z = (m & 4) ? sum.z * scale : 0.f;
    e4.w = (m & 8) ? sum.w * scale : 0.f;

    float* op = out + goff;
    #pragma unroll
    for (int k = 0; k < 8; ++k) {
        *reinterpret_cast<float4*>(op + (size_t)(32 * k) * HW) =
            make_float4(v[k].x + e4.x, v[k].y + e4.y, v[k].z + e4.z, v[k].w + e4.w);
    }
}

extern "C" void kernel_launch(void* const* d_in, const int* in_sizes, int n_in,
                              void* d_out, int out_size, void* d_ws, size_t ws_size,
                              hipStream_t stream) {
    const float* x  = (const float*)d_in[0];
    const float* bb = (const float*)d_in[1];
    const int* stride_p = (const int*)d_in[2];
    const int* epoch_p  = (const int*)d_in[3];
    float* out = (float*)d_out;

    int grid = N_ * H_ * 2;   // 2048 blocks, one per 64-pixel tile
    fused_exc_kernel<<<grid, 512, 0, stream>>>(x, bb, stride_p, epoch_p, out);
}

// Round 5
// 47.723 us; speedup vs baseline: 1.5511x; 1.0180x over previous
//
#include <hip/hip_runtime.h>
#include <math.h>

constexpr int N_ = 8, C_ = 256, H_ = 128, W_ = 128, G_ = 32;
constexpr int HW  = H_ * W_;        // 16384
constexpr int CHW = C_ * HW;        // 4194304
constexpr int TPIX = 64;            // pixels per tile (half a row)

typedef float f4 __attribute__((ext_vector_type(4)));

// Register-resident fused kernel + NON-TEMPORAL output stores.
// Tile = 64 pixels x 256 channels; 512 threads, 8 f4 per thread in registers.
// Boxes are read via wave-uniform (scalar-cache) loads -- no LDS, no race:
// the mask computes entirely in the shadow of the x loads.
// nt stores keep `out` from evicting x out of the 256 MiB L3.
__global__ __launch_bounds__(512) void fused_exc_kernel(
    const float* __restrict__ x, const float* __restrict__ bb,
    const int* __restrict__ stride_p, const int* __restrict__ epoch_p,
    float* __restrict__ out)
{
    __shared__ f4 psum[8][16];        // 2 KiB wave partials

    int bid  = blockIdx.x;
    int n    = bid >> 8;              // 8 n
    int rem  = bid & 255;
    int row  = rem >> 1;              // 128 rows
    int half = rem & 1;               // 2 half-rows

    int tid  = threadIdx.x;
    int wv   = tid >> 6;              // wave 0..7
    int lane = tid & 63;
    int c0   = tid >> 4;              // channel group 0..31
    int q    = tid & 15;              // f4 index within the 64-pixel tile

    size_t goff = (size_t)n * CHW + (size_t)c0 * HW + (size_t)row * W_ + half * TPIX + q * 4;
    const float* xp = x + goff;

    // Issue all 8 loads first -- mask below is independent of them,
    // so it executes while vmcnt is outstanding.
    f4 v[8];
    #pragma unroll
    for (int k = 0; k < 8; ++k)
        v[k] = *reinterpret_cast<const f4*>(xp + (size_t)(32 * k) * HW);

    // --- independent of x: schedule scalars + per-pixel mask (4 pixels) ---
    float inv   = 1.0f / (float)(*stride_p);
    float alpha = 0.5f * (1.0f + cosf((float)M_PI * (float)(*epoch_p) / 22.0f));
    float scale = alpha / (float)C_;

    float hf = (float)row;
    float w0 = (float)(half * TPIX + q * 4);
    const f4* bbp = reinterpret_cast<const f4*>(bb) + n * G_;   // wave-uniform
    int m = 0;
    #pragma unroll 4
    for (int g = 0; g < G_; ++g) {
        f4 bv = bbp[g];               // uniform index -> s_load_dwordx4
        float x1 = floorf(bv.x * inv), y1 = floorf(bv.y * inv);
        float x2 = ceilf (bv.z * inv), y2 = ceilf (bv.w * inv);
        if (hf >= y1 && hf < y2) {
            #pragma unroll
            for (int j = 0; j < 4; ++j) {
                float wf = w0 + (float)j;
                if (wf >= x1 && wf < x2) m |= 1 << j;
            }
        }
    }

    // --- channel reduction ---
    f4 s = v[0];
    #pragma unroll
    for (int k = 1; k < 8; ++k) s += v[k];
    s.x += __shfl_xor(s.x, 16); s.y += __shfl_xor(s.y, 16);
    s.z += __shfl_xor(s.z, 16); s.w += __shfl_xor(s.w, 16);
    s.x += __shfl_xor(s.x, 32); s.y += __shfl_xor(s.y, 32);
    s.z += __shfl_xor(s.z, 32); s.w += __shfl_xor(s.w, 32);
    if (lane < 16) psum[wv][q] = s;   // 32-channel partial for this wave
    __syncthreads();

    f4 sum = psum[0][q];
    #pragma unroll
    for (int w = 1; w < 8; ++w) sum += psum[w][q];

    f4 e4;
    e4.x = (m & 1) ? sum.x * scale : 0.f;
    e4.y = (m & 2) ? sum.y * scale : 0.f;
    e4.z = (m & 4) ? sum.z * scale : 0.f;
    e4.w = (m & 8) ? sum.w * scale : 0.f;

    float* op = out + goff;
    #pragma unroll
    for (int k = 0; k < 8; ++k) {
        f4 o = v[k] + e4;
        __builtin_nontemporal_store(o, reinterpret_cast<f4*>(op + (size_t)(32 * k) * HW));
    }
}

extern "C" void kernel_launch(void* const* d_in, const int* in_sizes, int n_in,
                              void* d_out, int out_size, void* d_ws, size_t ws_size,
                              hipStream_t stream) {
    const float* x  = (const float*)d_in[0];
    const float* bb = (const float*)d_in[1];
    const int* stride_p = (const int*)d_in[2];
    const int* epoch_p  = (const int*)d_in[3];
    float* out = (float*)d_out;

    int grid = N_ * H_ * 2;   // 2048 blocks, one per 64-pixel tile
    fused_exc_kernel<<<grid, 512, 0, stream>>>(x, bb, stride_p, epoch_p, out);
}